// Round 2
// baseline (143.930 us; speedup 1.0000x reference)
//
#include <hip/hip_runtime.h>
#include <hip/hip_bf16.h>
#include <math.h>

#define KMIX 16
#define DIM  16
#define SPT  4      // samples per thread in gmm_main

// ---------------------------------------------------------------------------
// Precompute: 4 blocks x 64 threads. Each block = ONE wave handling 4
// mixtures (16 lanes per matrix), so every __syncthreads is a single-wave
// barrier (near-free). Approx rcp/sqrt/rsq (v_rcp_f32 etc.) — abs tolerance
// is 0.675, we run at 0.06.
// Outputs:
//   wsA [K][16][16] dense rows of Linv (upper zero-padded, float4-aligned)
//   wsB [K][16]     b_k = Linv*mu
//   wsC [K]         Phi_k / sqrt(2*pi*det)
// ---------------------------------------------------------------------------
__global__ __launch_bounds__(64) void gmm_precompute(
    const float* __restrict__ Phi, const float* __restrict__ mu,
    const float* __restrict__ Sigma,
    float* __restrict__ wsA, float* __restrict__ wsB, float* __restrict__ wsC)
{
    __shared__ float A[4][DIM][DIM + 1];
    __shared__ float Li[4][DIM][DIM + 1];
    const int lane = threadIdx.x;
    const int kl = lane >> 4;            // local matrix 0..3
    const int i  = lane & 15;            // row (or column for substitution)
    const int k  = blockIdx.x * 4 + kl;  // global mixture

    for (int j = 0; j < DIM; ++j) A[kl][i][j] = Sigma[(k * DIM + i) * DIM + j];
    __syncthreads();

    // Right-looking Cholesky, lower triangle.
    for (int j = 0; j < DIM; ++j) {
        if (i == j) A[kl][j][j] = __builtin_amdgcn_sqrtf(A[kl][j][j]);
        __syncthreads();
        const float rd = __builtin_amdgcn_rcpf(A[kl][j][j]);
        if (i > j) A[kl][i][j] *= rd;
        __syncthreads();
        if (i > j) {
            const float lij = A[kl][i][j];
            for (int m = j + 1; m <= i; ++m) A[kl][i][m] -= lij * A[kl][m][j];
        }
        __syncthreads();
    }

    // Forward substitution: lane's column c, solve L y = e_c.
    {
        const int c = i;
        float y[DIM];
        #pragma unroll
        for (int r = 0; r < DIM; ++r) y[r] = 0.0f;
        #pragma unroll
        for (int r = 0; r < DIM; ++r) {
            if (r >= c) {
                float s = (r == c) ? 1.0f : 0.0f;
                for (int m = c; m < r; ++m) s -= A[kl][r][m] * y[m];
                y[r] = s * __builtin_amdgcn_rcpf(A[kl][r][r]);
            }
            Li[kl][r][c] = y[r];
        }
    }
    __syncthreads();

    if (i == 0) {
        float det = 1.0f;
        for (int j = 0; j < DIM; ++j) { const float d = A[kl][j][j]; det *= d * d; }
        wsC[k] = Phi[k] * __builtin_amdgcn_rsqf(2.0f * 3.14159265358979323846f * det);
    }
    float b = 0.0f;
    for (int j = 0; j <= i; ++j) b += Li[kl][i][j] * mu[k * DIM + j];
    wsB[k * DIM + i] = b;
    for (int j = 0; j < DIM; ++j)
        wsA[(k * DIM + i) * DIM + j] = (j <= i) ? Li[kl][i][j] : 0.0f;
}

// ---------------------------------------------------------------------------
// Main: 4 samples per thread to amortize constant loads (float4 rows of
// dense Linv). Per mixture: 45 VMEM instrs vs 608 FMAs -> VALU-bound.
// quad_k = || Linv_k x - b_k ||^2.
// ---------------------------------------------------------------------------
__global__ __launch_bounds__(256, 2) void gmm_main(
    const float* __restrict__ samples,
    const float* __restrict__ wsA, const float* __restrict__ wsB,
    const float* __restrict__ wsC, float* __restrict__ out, int N)
{
    const int base = blockIdx.x * (256 * SPT) + threadIdx.x;

    float x[SPT][DIM];
    #pragma unroll
    for (int s = 0; s < SPT; ++s) {
        const int idx = base + s * 256;
        if (idx < N) {
            const float4* p = (const float4*)samples + (size_t)idx * 4;
            const float4 a = p[0], b = p[1], c = p[2], d = p[3];
            x[s][0]=a.x;  x[s][1]=a.y;  x[s][2]=a.z;  x[s][3]=a.w;
            x[s][4]=b.x;  x[s][5]=b.y;  x[s][6]=b.z;  x[s][7]=b.w;
            x[s][8]=c.x;  x[s][9]=c.y;  x[s][10]=c.z; x[s][11]=c.w;
            x[s][12]=d.x; x[s][13]=d.y; x[s][14]=d.z; x[s][15]=d.w;
        } else {
            #pragma unroll
            for (int j = 0; j < DIM; ++j) x[s][j] = 0.0f;
        }
    }

    float sum[SPT];
    #pragma unroll
    for (int s = 0; s < SPT; ++s) sum[s] = 0.0f;

    for (int k = 0; k < KMIX; ++k) {
        const float4* __restrict__ Ak = (const float4*)(wsA + k * DIM * DIM);
        const float4* __restrict__ Bk = (const float4*)(wsB + k * DIM);
        const float ck = wsC[k];

        float bb[DIM];
        #pragma unroll
        for (int c = 0; c < 4; ++c) {
            const float4 v = Bk[c];
            bb[4*c+0]=v.x; bb[4*c+1]=v.y; bb[4*c+2]=v.z; bb[4*c+3]=v.w;
        }

        float q[SPT];
        #pragma unroll
        for (int s = 0; s < SPT; ++s) q[s] = 0.0f;

        #pragma unroll
        for (int i = 0; i < DIM; ++i) {
            const int nch = (i >> 2) + 1;    // float4 chunks holding cols 0..i
            float rr[DIM];
            #pragma unroll
            for (int c = 0; c < 4; ++c) {
                if (c < nch) {
                    const float4 v = Ak[i * 4 + c];
                    rr[4*c+0]=v.x; rr[4*c+1]=v.y; rr[4*c+2]=v.z; rr[4*c+3]=v.w;
                }
            }
            float y[SPT];
            #pragma unroll
            for (int s = 0; s < SPT; ++s) y[s] = -bb[i];
            #pragma unroll
            for (int j = 0; j < DIM; ++j) {
                if (j <= i) {   // compile-time folded: only lower triangle
                    #pragma unroll
                    for (int s = 0; s < SPT; ++s)
                        y[s] = fmaf(rr[j], x[s][j], y[s]);
                }
            }
            #pragma unroll
            for (int s = 0; s < SPT; ++s) q[s] = fmaf(y[s], y[s], q[s]);
        }

        #pragma unroll
        for (int s = 0; s < SPT; ++s)
            sum[s] = fmaf(ck, __expf(-0.5f * q[s]), sum[s]);
    }

    #pragma unroll
    for (int s = 0; s < SPT; ++s) {
        const int idx = base + s * 256;
        if (idx < N) out[idx] = -__logf(sum[s]);
    }
}

extern "C" void kernel_launch(void* const* d_in, const int* in_sizes, int n_in,
                              void* d_out, int out_size, void* d_ws, size_t ws_size,
                              hipStream_t stream)
{
    const float* samples = (const float*)d_in[0];
    const float* Phi     = (const float*)d_in[1];
    const float* mu      = (const float*)d_in[2];
    const float* Sigma   = (const float*)d_in[3];
    float* out = (float*)d_out;
    const int N = in_sizes[0] / DIM;

    float* wsA = (float*)d_ws;               // K*256 floats, dense Linv
    float* wsB = wsA + KMIX * DIM * DIM;     // K*16
    float* wsC = wsB + KMIX * DIM;           // K

    gmm_precompute<<<4, 64, 0, stream>>>(Phi, mu, Sigma, wsA, wsB, wsC);

    const int grid = (N + 256 * SPT - 1) / (256 * SPT);
    gmm_main<<<grid, 256, 0, stream>>>(samples, wsA, wsB, wsC, out, N);
}

// Round 3
// 106.546 us; speedup vs baseline: 1.3509x; 1.3509x over previous
//
#include <hip/hip_runtime.h>
#include <hip/hip_bf16.h>
#include <math.h>

#define KMIX 16
#define DIM  16
#define TPW  8          // 16-sample tiles per wave in gmm_main
#define TRI_IDX(i,j) (((i)*((i)+1))/2 + (j))

typedef _Float16 half8 __attribute__((ext_vector_type(8)));
typedef float    f32x4 __attribute__((ext_vector_type(4)));

// ---------------------------------------------------------------------------
// Precompute: ONE wave. Lane k<16 factors Sigma_k = L L^T and inverts L
// entirely in registers with compile-time-unrolled triangular loops (no LDS
// in the dependent chain -> no 120-cyc ds_read latency chain, no barriers).
// Then all 64 lanes pack the MFMA A-operand fragments:
//   wsA[mix][lane] = half8 of W~[m=lane&15][k=quad*8+j], where
//   W~ = [ L^{-1} | -b | 0-pad ]  (16 x 32), b = L^{-1} mu.
//   wsC[mix] = Phi / sqrt(2*pi*det)
// ---------------------------------------------------------------------------
__global__ __launch_bounds__(64) void gmm_precompute(
    const float* __restrict__ Phi, const float* __restrict__ mu,
    const float* __restrict__ Sigma,
    _Float16* __restrict__ wsA, float* __restrict__ wsC)
{
    __shared__ float sLi[KMIX][DIM][DIM];   // L^{-1}, upper part zeroed
    __shared__ float sNB[KMIX][DIM];        // -b
    const int lane = threadIdx.x;

    if (lane < KMIX) {
        const int k = lane;
        float a[136], li[136], rd[DIM];

        #pragma unroll
        for (int i = 0; i < DIM; ++i)
            #pragma unroll
            for (int j = 0; j <= i; ++j)
                a[TRI_IDX(i, j)] = Sigma[k * 256 + i * 16 + j];

        // Left-looking Cholesky, in place, reciprocal diagonal kept.
        #pragma unroll
        for (int i = 0; i < DIM; ++i) {
            #pragma unroll
            for (int j = 0; j <= i; ++j) {
                float s = a[TRI_IDX(i, j)];
                #pragma unroll
                for (int m = 0; m < j; ++m)
                    s -= a[TRI_IDX(i, m)] * a[TRI_IDX(j, m)];
                if (j == i) {
                    const float d = __builtin_amdgcn_sqrtf(s);
                    a[TRI_IDX(i, i)] = d;
                    rd[i] = __builtin_amdgcn_rcpf(d);
                } else {
                    a[TRI_IDX(i, j)] = s * rd[j];
                }
            }
        }

        // li = L^{-1} (forward substitution per column, compile-time bounds)
        #pragma unroll
        for (int c = 0; c < DIM; ++c) {
            li[TRI_IDX(c, c)] = rd[c];
            #pragma unroll
            for (int r = c + 1; r < DIM; ++r) {
                float s = 0.0f;
                #pragma unroll
                for (int m = c; m < r; ++m)
                    s += a[TRI_IDX(r, m)] * li[TRI_IDX(m, c)];
                li[TRI_IDX(r, c)] = -s * rd[r];
            }
        }

        // coeff = Phi / (sqrt(2*pi) * prod(diag))
        float invd = 1.0f;
        #pragma unroll
        for (int i = 0; i < DIM; ++i) invd *= rd[i];
        wsC[k] = Phi[k] * 0.3989422804014327f * invd;

        // b = L^{-1} mu; publish L^{-1} (zero-padded) and -b to LDS
        float mv[DIM];
        #pragma unroll
        for (int j = 0; j < DIM; ++j) mv[j] = mu[k * DIM + j];
        #pragma unroll
        for (int r = 0; r < DIM; ++r) {
            float b = 0.0f;
            #pragma unroll
            for (int j = 0; j <= r; ++j) b += li[TRI_IDX(r, j)] * mv[j];
            sNB[k][r] = -b;
            #pragma unroll
            for (int j = 0; j < DIM; ++j)
                sLi[k][r][j] = (j <= r) ? li[TRI_IDX(r, j)] : 0.0f;
        }
    }
    __syncthreads();

    // All 64 lanes: pack A-operand fragments (verified 16x16x32 A layout:
    // A[m = lane&15][k = quad*8 + j]).
    const int m = lane & 15;
    const int quad = lane >> 4;
    for (int mix = 0; mix < KMIX; ++mix) {
        half8 h;
        #pragma unroll
        for (int j = 0; j < 8; ++j) {
            float v;
            if (quad == 0)      v = sLi[mix][m][j];
            else if (quad == 1) v = sLi[mix][m][8 + j];
            else if (quad == 2) v = (j == 0) ? sNB[mix][m] : 0.0f;
            else                v = 0.0f;
            h[j] = (_Float16)v;
        }
        ((half8*)wsA)[mix * 64 + lane] = h;
    }
}

// ---------------------------------------------------------------------------
// Main: per wave, per 16-sample tile: build B frag = [x;1;0-pad] columns,
// one MFMA per mixture -> y[comp][sample], q = sum comp y^2 via 4 local
// square-FMAs + shfl_xor(16) + shfl_xor(32), then sum_k c_k exp(-q/2).
// ---------------------------------------------------------------------------
__global__ __launch_bounds__(256) void gmm_main(
    const float* __restrict__ samples,
    const _Float16* __restrict__ wsA, const float* __restrict__ wsC,
    float* __restrict__ out, int N, int ntiles)
{
    const int lane = threadIdx.x & 63;
    const int wave = blockIdx.x * (blockDim.x >> 6) + (threadIdx.x >> 6);
    const int n = lane & 15;          // sample column within tile
    const int quad = lane >> 4;

    // Loop-invariant: A fragments (16 mixtures) + coefficients.
    half8 afrag[KMIX];
    #pragma unroll
    for (int mix = 0; mix < KMIX; ++mix)
        afrag[mix] = ((const half8*)wsA)[mix * 64 + lane];
    float ck[KMIX];
    #pragma unroll
    for (int mix = 0; mix < KMIX; ++mix) ck[mix] = wsC[mix];

    const f32x4 zero = {0.0f, 0.0f, 0.0f, 0.0f};

    for (int t = 0; t < TPW; ++t) {
        const int tile = wave * TPW + t;
        if (tile >= ntiles) break;
        const int s0 = tile * 16;

        // B frag: B[k = quad*8+j][n] = x~[sample n][k]
        half8 bfrag;
        #pragma unroll
        for (int j = 0; j < 8; ++j) bfrag[j] = (_Float16)0.0f;
        if (quad < 2) {
            int sidx = s0 + n; if (sidx >= N) sidx = N - 1;
            const float4* p = (const float4*)(samples + (size_t)sidx * DIM + quad * 8);
            const float4 u = p[0], v = p[1];
            bfrag[0] = (_Float16)u.x; bfrag[1] = (_Float16)u.y;
            bfrag[2] = (_Float16)u.z; bfrag[3] = (_Float16)u.w;
            bfrag[4] = (_Float16)v.x; bfrag[5] = (_Float16)v.y;
            bfrag[6] = (_Float16)v.z; bfrag[7] = (_Float16)v.w;
        } else if (quad == 2) {
            bfrag[0] = (_Float16)1.0f;   // augmented k=16 -> folds -b
        }

        float sum = 0.0f;
        #pragma unroll
        for (int mix = 0; mix < KMIX; ++mix) {
            const f32x4 d = __builtin_amdgcn_mfma_f32_16x16x32_f16(
                afrag[mix], bfrag, zero, 0, 0, 0);
            float q = d[0] * d[0];
            q = fmaf(d[1], d[1], q);
            q = fmaf(d[2], d[2], q);
            q = fmaf(d[3], d[3], q);
            q += __shfl_xor(q, 16, 64);
            q += __shfl_xor(q, 32, 64);
            sum = fmaf(ck[mix], __expf(-0.5f * q), sum);
        }

        const int sidx = s0 + n;
        if (quad == 0 && sidx < N) out[sidx] = -__logf(sum);
    }
}

extern "C" void kernel_launch(void* const* d_in, const int* in_sizes, int n_in,
                              void* d_out, int out_size, void* d_ws, size_t ws_size,
                              hipStream_t stream)
{
    const float* samples = (const float*)d_in[0];
    const float* Phi     = (const float*)d_in[1];
    const float* mu      = (const float*)d_in[2];
    const float* Sigma   = (const float*)d_in[3];
    float* out = (float*)d_out;
    const int N = in_sizes[0] / DIM;

    _Float16* wsA = (_Float16*)d_ws;                       // 16*64*8 halves = 16 KB
    float* wsC = (float*)((char*)d_ws + KMIX * 64 * 8 * sizeof(_Float16));

    gmm_precompute<<<1, 64, 0, stream>>>(Phi, mu, Sigma, wsA, wsC);

    const int ntiles = (N + 15) / 16;
    const int waves  = (ntiles + TPW - 1) / TPW;
    const int blocks = (waves + 3) / 4;
    gmm_main<<<blocks, 256, 0, stream>>>(samples, wsA, wsC, out, N, ntiles);
}